// Round 4
// baseline (12102.981 us; speedup 1.0000x reference)
//
#include <hip/hip_runtime.h>
#include <cstdint>
#include <cstddef>

// ---------------------------------------------------------------------------
// LSTM TF-autoencoder, persistent-kernel, poison-poll sync (no flags).
//  grid = 8 batch-groups (16 rows) x 16 gate-row slices = 128 blocks, 256 thr.
//
// THIS ROUND (R3 post-mortem: local sc0/L2 path WORKS - FETCH collapsed 6x
// with correct data - but buffer_inv before every read cost +1.6us/step):
//  * DROP buffer_inv entirely. `sc0` on a load is the glc-lineage coherent
//    bit: bypasses/refreshes L1 and reads the shared XCD L2, which already
//    holds the producer's sc0 store (write-through). R3 proved data
//    correctness of this path; the inv was redundant.
//  * Keep: dedicated claim table (R2's NaN root cause was table/ring
//    aliasing), double-store (sc0 sc1 authoritative for escalated/system
//    readers + sc0 fast L2 copy), tiered poll (8 fast L2 tries then
//    escalate to sc0 sc1 system loads -> self-healing if the no-inv model
//    is wrong: degrades to the R1 protocol instead of deadman->NaN).
//  * Non-local (spill) groups run the R1 system-scope protocol unchanged.
//
// Encoder is layer-skewed (iter t = layer0(t) + layer1(t-1)); decoder carries
// polled h0/h1 in VGPRs across steps. Poison protocol as derived in R1.
// ---------------------------------------------------------------------------

typedef _Float16 f16x8 __attribute__((ext_vector_type(8)));
typedef float    f32x4 __attribute__((ext_vector_type(4)));
typedef unsigned int u32x4 __attribute__((ext_vector_type(4)));

#define AROWS 608  // LDS A-tile row stride in halfs

// workspace layout (bytes)
constexpr size_t OFF_E0  = 0;         // enc L0 packed [1024 x 320] f16
constexpr size_t OFF_E1  = 655360;    // enc L1 packed [1024 x 512] f16
constexpr size_t OFF_D0  = 1703936;   // dec L0 packed
constexpr size_t OFF_D1  = 2359296;   // dec L1 packed
constexpr size_t OFF_OW  = 3407872;   // out_W^T packed [256 x 64] f16
constexpr size_t OFF_H0  = 3440640;   // h0 ring: 4 slots x 65536 B
constexpr size_t OFF_H1  = 3702784;   // h1 ring: 4 slots x 65536 B
constexpr size_t OFF_XH  = 3964928;   // x in f16 [128][1024][64]
constexpr size_t OFF_TBL = 20742144;  // XCD claim table (dedicated, 512 B)
// slot layout (halfs): slot*32768 + g*4096 + r*256 + b*16 + th

// MODE 0 = local (sc0: L1-bypass, probe shared XCD L2)
// MODE 1 = system (sc0 sc1: LLC)
template<int MODE>
__device__ __forceinline__ void ldg2_m(const void* p0, const void* p1, u32x4& a, u32x4& b){
  if constexpr(MODE == 0)
    asm volatile("global_load_dwordx4 %0, %2, off sc0\n\t"
                 "global_load_dwordx4 %1, %3, off sc0\n\t"
                 "s_waitcnt vmcnt(0)"
                 : "=&v"(a), "=&v"(b)
                 : "v"((unsigned long long)(uintptr_t)p0),
                   "v"((unsigned long long)(uintptr_t)p1) : "memory");
  else
    asm volatile("global_load_dwordx4 %0, %2, off sc0 sc1\n\t"
                 "global_load_dwordx4 %1, %3, off sc0 sc1\n\t"
                 "s_waitcnt vmcnt(0)"
                 : "=&v"(a), "=&v"(b)
                 : "v"((unsigned long long)(uintptr_t)p0),
                   "v"((unsigned long long)(uintptr_t)p1) : "memory");
}
template<int MODE>
__device__ __forceinline__ void ldg4_m(const void* p0, const void* p1, const void* p2, const void* p3,
                                       u32x4& a, u32x4& b, u32x4& c, u32x4& d){
  if constexpr(MODE == 0)
    asm volatile("global_load_dwordx4 %0, %4, off sc0\n\t"
                 "global_load_dwordx4 %1, %5, off sc0\n\t"
                 "global_load_dwordx4 %2, %6, off sc0\n\t"
                 "global_load_dwordx4 %3, %7, off sc0\n\t"
                 "s_waitcnt vmcnt(0)"
                 : "=&v"(a), "=&v"(b), "=&v"(c), "=&v"(d)
                 : "v"((unsigned long long)(uintptr_t)p0),
                   "v"((unsigned long long)(uintptr_t)p1),
                   "v"((unsigned long long)(uintptr_t)p2),
                   "v"((unsigned long long)(uintptr_t)p3) : "memory");
  else
    asm volatile("global_load_dwordx4 %0, %4, off sc0 sc1\n\t"
                 "global_load_dwordx4 %1, %5, off sc0 sc1\n\t"
                 "global_load_dwordx4 %2, %6, off sc0 sc1\n\t"
                 "global_load_dwordx4 %3, %7, off sc0 sc1\n\t"
                 "s_waitcnt vmcnt(0)"
                 : "=&v"(a), "=&v"(b), "=&v"(c), "=&v"(d)
                 : "v"((unsigned long long)(uintptr_t)p0),
                   "v"((unsigned long long)(uintptr_t)p1),
                   "v"((unsigned long long)(uintptr_t)p2),
                   "v"((unsigned long long)(uintptr_t)p3) : "memory");
}

// store: system-authoritative always; LOCAL adds a same-data fast L2 copy.
template<bool LOCAL>
__device__ __forceinline__ void st_coh128(void* p, u32x4 v){
  asm volatile("global_store_dwordx4 %0, %1, off sc0 sc1"
               :: "v"((unsigned long long)(uintptr_t)p), "v"(v) : "memory");
  if constexpr(LOCAL)
    asm volatile("global_store_dwordx4 %0, %1, off sc0"
                 :: "v"((unsigned long long)(uintptr_t)p), "v"(v) : "memory");
}

// eager reads (validated later): LOCAL = L2 probe; else system.
template<bool LOCAL>
__device__ __forceinline__ void ldg2_coh(const void* p0, const void* p1, u32x4& a, u32x4& b){
  if constexpr(LOCAL) ldg2_m<0>(p0, p1, a, b);
  else                ldg2_m<1>(p0, p1, a, b);
}
template<bool LOCAL>
__device__ __forceinline__ void ldg4_coh(const void* p0, const void* p1, const void* p2, const void* p3,
                                         u32x4& a, u32x4& b, u32x4& c, u32x4& d){
  if constexpr(LOCAL) ldg4_m<0>(p0, p1, p2, p3, a, b, c, d);
  else                ldg4_m<1>(p0, p1, p2, p3, a, b, c, d);
}

// retry-poll: LOCAL does 8 fast L2 tries then escalates to system loads.
template<bool LOCAL>
__device__ __forceinline__ void poll2(const void* p0, const void* p1,
                                      u32x4& a, u32x4& b, int& dead){
  if(dead) return;
  for(int gu = 0;; ++gu){
    if(LOCAL && gu < 8) ldg2_m<0>(p0, p1, a, b);
    else                ldg2_m<1>(p0, p1, a, b);
    unsigned bad = 0;
#pragma unroll
    for(int j = 0; j < 4; ++j) bad |= (a[j]==0xFFFFFFFFu) | (b[j]==0xFFFFFFFFu);
    if(!bad) return;
    if(gu > 60000){ dead = 1; return; }
  }
}

// system-scope scalar ops for the claim table
__device__ __forceinline__ int ldg_sys_i32(const int* p){
  int v;
  asm volatile("global_load_dword %0, %1, off sc0 sc1\n\ts_waitcnt vmcnt(0)"
               : "=v"(v) : "v"((unsigned long long)(uintptr_t)p) : "memory");
  return v;
}
__device__ __forceinline__ void stg_sys_i32(int* p, int v){
  asm volatile("global_store_dword %0, %1, off sc0 sc1"
               :: "v"((unsigned long long)(uintptr_t)p), "v"(v) : "memory");
}

__device__ __forceinline__ float sigm(float z){ return 1.f/(1.f + __expf(-z)); }
__device__ __forceinline__ float tanh_(float z){ return 2.f/(1.f + __expf(-2.f*z)) - 1.f; }

template<int KS>
__device__ __forceinline__ f32x4 gemm_tile(const _Float16* A, int am, int q, const f16x8* wf){
  f32x4 a0 = {0.f,0.f,0.f,0.f}, a1 = {0.f,0.f,0.f,0.f};
#pragma unroll
  for(int ks = 0; ks < KS; ++ks){
    f16x8 av = *(const f16x8*)(A + am*AROWS + ks*32 + q*8);
    if(ks & 1) a1 = __builtin_amdgcn_mfma_f32_16x16x32_f16(av, wf[ks], a1, 0, 0, 0);
    else       a0 = __builtin_amdgcn_mfma_f32_16x16x32_f16(av, wf[ks], a0, 0, 0, 0);
  }
  return a0 + a1;
}

// ---------------- prep kernels ---------------------------------------------
__global__ void lstm_xcvt(const float* __restrict__ xin, _Float16* __restrict__ xh){
  size_t i = ((size_t)blockIdx.x * 256 + threadIdx.x) * 8;
  float4 a = *(const float4*)(xin + i);
  float4 b = *(const float4*)(xin + i + 4);
  union { _Float16 h[8]; u32x4 v; } o;
  o.h[0]=(_Float16)a.x; o.h[1]=(_Float16)a.y; o.h[2]=(_Float16)a.z; o.h[3]=(_Float16)a.w;
  o.h[4]=(_Float16)b.x; o.h[5]=(_Float16)b.y; o.h[6]=(_Float16)b.z; o.h[7]=(_Float16)b.w;
  *(u32x4*)(xh + i) = o.v;
}

__global__ void lstm_packw(const float* eW0, const float* eU0, const float* eW1, const float* eU1,
                           const float* dW0, const float* dU0, const float* dW1, const float* dU1,
                           const float* oW, char* ws){
  int c = blockIdx.x * 256 + threadIdx.x;
  const float *Wih, *Whh; _Float16* dst; int KS, Kin, cc;
  if(c < 40960)      { Wih=eW0; Whh=eU0; dst=(_Float16*)(ws+OFF_E0); KS=10; Kin=64;  cc=c; }
  else if(c < 106496){ Wih=eW1; Whh=eU1; dst=(_Float16*)(ws+OFF_E1); KS=16; Kin=256; cc=c-40960; }
  else if(c < 147456){ Wih=dW0; Whh=dU0; dst=(_Float16*)(ws+OFF_D0); KS=10; Kin=64;  cc=c-106496; }
  else if(c < 212992){ Wih=dW1; Whh=dU1; dst=(_Float16*)(ws+OFF_D1); KS=16; Kin=256; cc=c-147456; }
  else{
    cc = c - 212992;
    int l = cc & 63, t1 = cc >> 6, ks = t1 & 7, nt = t1 >> 3;
    int n = nt*16 + (l & 15), kb = ks*32 + ((l >> 4) << 3);
    union { _Float16 h[8]; u32x4 v; } o;
#pragma unroll
    for(int j = 0; j < 8; ++j) o.h[j] = (_Float16)oW[n*256 + kb + j];
    *(u32x4*)((_Float16*)(ws + OFF_OW) + (size_t)cc*8) = o.v;
    return;
  }
  int l = cc & 63, t1 = cc >> 6, ks, t2;
  if(KS == 10){ ks = t1 % 10; t2 = t1 / 10; } else { ks = t1 & 15; t2 = t1 >> 4; }
  int rr = t2 & 15, wg = t2 >> 4;
  int row = wg*256 + rr*16 + (l & 15);
  int kb  = ks*32 + ((l >> 4) << 3);
  union { _Float16 h[8]; u32x4 v; } o;
#pragma unroll
  for(int j = 0; j < 8; ++j){
    int k = kb + j;
    float s = (k < Kin) ? Wih[row*Kin + k] : Whh[row*256 + (k - Kin)];
    o.h[j] = (_Float16)s;
  }
  *(u32x4*)(dst + (size_t)cc*8) = o.v;
}

// ---------------- shared-memory block --------------------------------------
struct Shm {
  alignas(16) _Float16 Abuf[16*AROWS];
  float zbuf[4][16][17];
  alignas(16) _Float16 dinbuf[16][80];
  alignas(16) _Float16 hsh[256];
};

// ---------------- core (templated on exchange scope) -----------------------
template<bool LOCAL>
__device__ __forceinline__ void core(
    const float* __restrict__ x, const int* __restrict__ lengths,
    const int* __restrict__ tf,
    const float* __restrict__ eb0, const float* __restrict__ eb1,
    const float* __restrict__ db0, const float* __restrict__ db1,
    const float* __restrict__ outb,
    float* __restrict__ dout, char* __restrict__ ws,
    const int g, const int r, Shm* sh)
{
  const int tid = threadIdx.x;
  const int lane = tid & 63, w = tid >> 6;
  const int gb = g * 16;
  const int tb = tid >> 4, th = tid & 15;
  const int am = lane & 15, q = lane >> 4;
  const int m0 = tid >> 5, kc = tid & 31;
  const int hco = (kc >> 1)*256 + (kc & 1)*8 + m0*16 + g*4096; // + slot*32768
  const int slice = g*4096 + r*256;                            // writer slice base

  _Float16* Xh    = (_Float16*)(ws + OFF_XH);
  _Float16* h0buf = (_Float16*)(ws + OFF_H0);
  _Float16* h1buf = (_Float16*)(ws + OFF_H1);
  float* outD = dout;
  float* outE = dout + (size_t)128*1024*64;

  _Float16* Abuf = sh->Abuf;
  auto& zbuf   = sh->zbuf;
  auto& dinbuf = sh->dinbuf;
  _Float16* hsh = sh->hsh;

  float c0 = 0.f, c1 = 0.f, h0p = 0.f, h1p = 0.f;
  const int len_b = lengths[gb + tb];
  int dead = 0;
  const u32x4 PZ = {0xFFFFFFFFu,0xFFFFFFFFu,0xFFFFFFFFu,0xFFFFFFFFu};

  u32x4 H0ra, H0rb;  // carried full-h0 chunks
  u32x4 H1ca, H1cb;  // carried full-h1 chunks

  float be0[4], be1[4];
#pragma unroll
  for(int j = 0; j < 4; ++j){
    be0[j] = eb0[j*256 + r*16 + th];
    be1[j] = eb1[j*256 + r*16 + th];
  }

  f16x8 wf0[10], wf1[16], wfo[8];
  {
    const f16x8* p0 = (const f16x8*)(ws + OFF_E0);
    const f16x8* p1 = (const f16x8*)(ws + OFF_E1);
#pragma unroll
    for(int ks = 0; ks < 10; ++ks) wf0[ks] = p0[((w*16 + r)*10 + ks)*64 + lane];
#pragma unroll
    for(int ks = 0; ks < 16; ++ks) wf1[ks] = p1[((w*16 + r)*16 + ks)*64 + lane];
  }

  // ===================== ENCODER (layer-skewed) =====================
  for(int t = 0; t <= 1024; ++t){
    const int sh0 = (t+3)&3;   // h0(t-1) read slot
    const int sh1 = (t+2)&3;   // h1(t-2) read slot
    u32x4 a, b, H1a, H1b;
    const _Float16 *h1q0, *h1q1;

    // ---- stage: x_t + h0(t-1); issue h1(t-2) (validated after cell0) ----
    if(t < 1024 && tid < 128){
      int mm = tid >> 3, k0 = (tid & 7) * 8;
      *(f16x8*)(Abuf + mm*AROWS + k0) =
          *(const f16x8*)(Xh + ((size_t)(gb + mm)*1024 + t)*64 + k0);
    }
    {
      const _Float16* b0 = h0buf + sh0*32768 + hco;
      const _Float16* b1 = b0 + 128;
      h1q0 = h1buf + sh1*32768 + hco;
      h1q1 = h1q0 + 128;
      ldg4_coh<LOCAL>(b0, b1, h1q0, h1q1, a, b, H1a, H1b);
      unsigned bad = 0;
#pragma unroll
      for(int j = 0; j < 4; ++j) bad |= (a[j]==0xFFFFFFFFu) | (b[j]==0xFFFFFFFFu);
      if(bad) poll2<LOCAL>(b0, b1, a, b, dead);
      *(f16x8*)(Abuf + m0*AROWS + 64 + kc*8)     = __builtin_bit_cast(f16x8, a);
      *(f16x8*)(Abuf + (m0+8)*AROWS + 64 + kc*8) = __builtin_bit_cast(f16x8, b);
      H0ra = a; H0rb = b;   // live-out at t==1024: h0(enc,1023) for decoder A0
    }
    __syncthreads();

    if(t < 1024){
      { // layer0 GEMM
        f32x4 z = gemm_tile<10>(Abuf, am, q, wf0);
#pragma unroll
        for(int i = 0; i < 4; ++i) zbuf[w][q*4 + i][am] = z[i];
      }
      __syncthreads();
      { // layer0 cell (freeze past length)
        float zi = zbuf[0][tb][th] + be0[0];
        float zf = zbuf[1][tb][th] + be0[1];
        float zg = zbuf[2][tb][th] + be0[2];
        float zo = zbuf[3][tb][th] + be0[3];
        float cn = sigm(zf)*c0 + sigm(zi)*tanh_(zg);
        float hn = sigm(zo)*tanh_(cn);
        bool valid = t < len_b;
        c0  = valid ? cn : c0;
        h0p = valid ? hn : h0p;
        hsh[tb*16 + th] = (_Float16)h0p;
      }
      __syncthreads();
      if(tid < 32)
        st_coh128<LOCAL>(h0buf + (t&3)*32768 + slice + tid*8, *(const u32x4*)&hsh[tid*8]);
    }

    if(t >= 1){
      // ---- validate h1(t-2), stage A[320,576), poison ----
      unsigned bad = 0;
#pragma unroll
      for(int j = 0; j < 4; ++j) bad |= (H1a[j]==0xFFFFFFFFu) | (H1b[j]==0xFFFFFFFFu);
      if(bad) poll2<LOCAL>(h1q0, h1q1, H1a, H1b, dead);
      *(f16x8*)(Abuf + m0*AROWS + 320 + kc*8)     = __builtin_bit_cast(f16x8, H1a);
      *(f16x8*)(Abuf + (m0+8)*AROWS + 320 + kc*8) = __builtin_bit_cast(f16x8, H1b);
      if(tid < 64){
        _Float16* basep = (tid < 32) ? (h0buf + ((t+2)&3)*32768)
                                     : (h1buf + ((t+1)&3)*32768);
        st_coh128<LOCAL>(basep + slice + (tid&31)*8, PZ);
      }
      __syncthreads();

      { // layer1 GEMM (step t-1)
        f32x4 z = gemm_tile<16>(Abuf + 64, am, q, wf1);
#pragma unroll
        for(int i = 0; i < 4; ++i) zbuf[w][q*4 + i][am] = z[i];
      }
      __syncthreads();
      { // layer1 cell for step u = t-1 (+ encoder output)
        const int u = t - 1;
        float zi = zbuf[0][tb][th] + be1[0];
        float zf = zbuf[1][tb][th] + be1[1];
        float zg = zbuf[2][tb][th] + be1[2];
        float zo = zbuf[3][tb][th] + be1[3];
        float cn = sigm(zf)*c1 + sigm(zi)*tanh_(zg);
        float hn = sigm(zo)*tanh_(cn);
        bool valid = u < len_b;
        c1  = valid ? cn : c1;
        h1p = valid ? hn : h1p;
        outE[((size_t)(gb + tb)*1024 + u)*256 + r*16 + th] = valid ? h1p : 0.f;
        hsh[tb*16 + th] = (_Float16)h1p;
      }
      __syncthreads();
      if(tid < 32)
        st_coh128<LOCAL>(h1buf + ((t+3)&3)*32768 + slice + tid*8, *(const u32x4*)&hsh[tid*8]);
    }
  }

  // ===================== phase switch =====================
  {
    const f16x8* p0 = (const f16x8*)(ws + OFF_D0);
    const f16x8* p1 = (const f16x8*)(ws + OFF_D1);
    const f16x8* po = (const f16x8*)(ws + OFF_OW);
#pragma unroll
    for(int ks = 0; ks < 10; ++ks) wf0[ks] = p0[((w*16 + r)*10 + ks)*64 + lane];
#pragma unroll
    for(int ks = 0; ks < 16; ++ks) wf1[ks] = p1[((w*16 + r)*16 + ks)*64 + lane];
#pragma unroll
    for(int ks = 0; ks < 8;  ++ks) wfo[ks] = po[(w*8 + ks)*64 + lane];
  }
  float bd0[4], bd1[4], ob[4];
#pragma unroll
  for(int j = 0; j < 4; ++j){
    bd0[j] = db0[j*256 + r*16 + th];
    bd1[j] = db1[j*256 + r*16 + th];
    ob[j]  = outb[th*4 + j];
  }
  { // dec_in init = x[:, T-1, :]
    float4 xv = *(const float4*)(x + ((size_t)(gb + tb)*1024 + 1023)*64 + th*4);
    dinbuf[tb][th*4 + 0] = (_Float16)xv.x;
    dinbuf[tb][th*4 + 1] = (_Float16)xv.y;
    dinbuf[tb][th*4 + 2] = (_Float16)xv.z;
    dinbuf[tb][th*4 + 3] = (_Float16)xv.w;
  }
  __syncthreads();

  // transition: poll h1(enc,1023) (slot 3) into carry regs; then poison the
  // stale h1 slot 2.
  {
    const _Float16* b0 = h1buf + 3*32768 + hco;
    const _Float16* b1 = b0 + 128;
    ldg2_coh<LOCAL>(b0, b1, H1ca, H1cb);
    unsigned bad = 0;
#pragma unroll
    for(int j = 0; j < 4; ++j) bad |= (H1ca[j]==0xFFFFFFFFu) | (H1cb[j]==0xFFFFFFFFu);
    if(bad) poll2<LOCAL>(b0, b1, H1ca, H1cb, dead);
  }
  if(tid < 32)
    st_coh128<LOCAL>(h1buf + 2*32768 + slice + tid*8, PZ);

  // ===================== DECODER =====================
  for(int d = 0; d < 1024; ++d){
    const int s4 = d & 3;

    // ---- stage A0 from dinbuf + carried h0(d-1) ----
    if(tid < 128){
      int mm = tid >> 3, k0 = (tid & 7) * 8;
      *(f16x8*)(Abuf + mm*AROWS + k0) = *(const f16x8*)(&dinbuf[mm][k0]);
    }
    *(f16x8*)(Abuf + m0*AROWS + 64 + kc*8)     = __builtin_bit_cast(f16x8, H0ra);
    *(f16x8*)(Abuf + (m0+8)*AROWS + 64 + kc*8) = __builtin_bit_cast(f16x8, H0rb);
    __syncthreads();

    {
      f32x4 z = gemm_tile<10>(Abuf, am, q, wf0);
#pragma unroll
      for(int i = 0; i < 4; ++i) zbuf[w][q*4 + i][am] = z[i];
    }
    __syncthreads();
    { // layer0 cell
      float zi = zbuf[0][tb][th] + bd0[0];
      float zf = zbuf[1][tb][th] + bd0[1];
      float zg = zbuf[2][tb][th] + bd0[2];
      float zo = zbuf[3][tb][th] + bd0[3];
      float cn = sigm(zf)*c0 + sigm(zi)*tanh_(zg);
      float hn = sigm(zo)*tanh_(cn);
      c0 = cn;
      hsh[tb*16 + th] = (_Float16)hn;
    }
    __syncthreads();
    if(tid < 32)
      st_coh128<LOCAL>(h0buf + s4*32768 + slice + tid*8, *(const u32x4*)&hsh[tid*8]);

    // ---- stage A1-right from carried h1(d-1); poll h0(d) -> A1-left ----
    *(f16x8*)(Abuf + m0*AROWS + 256 + kc*8)     = __builtin_bit_cast(f16x8, H1ca);
    *(f16x8*)(Abuf + (m0+8)*AROWS + 256 + kc*8) = __builtin_bit_cast(f16x8, H1cb);
    {
      const _Float16* b0 = h0buf + s4*32768 + hco;
      const _Float16* b1 = b0 + 128;
      u32x4 a, b;
      ldg2_coh<LOCAL>(b0, b1, a, b);
      unsigned bad = 0;
#pragma unroll
      for(int j = 0; j < 4; ++j) bad |= (a[j]==0xFFFFFFFFu) | (b[j]==0xFFFFFFFFu);
      if(bad) poll2<LOCAL>(b0, b1, a, b, dead);
      *(f16x8*)(Abuf + m0*AROWS + kc*8)       = __builtin_bit_cast(f16x8, a);
      *(f16x8*)(Abuf + (m0+8)*AROWS + kc*8)   = __builtin_bit_cast(f16x8, b);
      H0ra = a; H0rb = b;
    }
    if(tid < 64){
      _Float16* basep = ((tid < 32) ? h0buf : h1buf) + ((d+3)&3)*32768;
      st_coh128<LOCAL>(basep + slice + (tid&31)*8, PZ);
    }
    __syncthreads();

    {
      f32x4 z = gemm_tile<16>(Abuf, am, q, wf1);
#pragma unroll
      for(int i = 0; i < 4; ++i) zbuf[w][q*4 + i][am] = z[i];
    }
    __syncthreads();
    { // layer1 cell
      float zi = zbuf[0][tb][th] + bd1[0];
      float zf = zbuf[1][tb][th] + bd1[1];
      float zg = zbuf[2][tb][th] + bd1[2];
      float zo = zbuf[3][tb][th] + bd1[3];
      float cn = sigm(zf)*c1 + sigm(zi)*tanh_(zg);
      float hn = sigm(zo)*tanh_(cn);
      c1 = cn;
      hsh[tb*16 + th] = (_Float16)hn;
    }
    __syncthreads();
    if(tid < 32)
      st_coh128<LOCAL>(h1buf + s4*32768 + slice + tid*8, *(const u32x4*)&hsh[tid*8]);

    // ---- poll full h1(d) for output projection (also next A1-right) ----
    {
      const _Float16* b0 = h1buf + s4*32768 + hco;
      const _Float16* b1 = b0 + 128;
      ldg2_coh<LOCAL>(b0, b1, H1ca, H1cb);
      unsigned bad = 0;
#pragma unroll
      for(int j = 0; j < 4; ++j) bad |= (H1ca[j]==0xFFFFFFFFu) | (H1cb[j]==0xFFFFFFFFu);
      if(bad) poll2<LOCAL>(b0, b1, H1ca, H1cb, dead);
      *(f16x8*)(Abuf + m0*AROWS + kc*8)     = __builtin_bit_cast(f16x8, H1ca);
      *(f16x8*)(Abuf + (m0+8)*AROWS + kc*8) = __builtin_bit_cast(f16x8, H1cb);
    }
    __syncthreads();

    { // out projection: wave w -> D columns w*16..w*16+15
      f32x4 z = gemm_tile<8>(Abuf, am, q, wfo);
#pragma unroll
      for(int i = 0; i < 4; ++i) zbuf[w][q*4 + i][am] = z[i];
    }
    __syncthreads();

    { // assemble out, write d_out (balanced: block r writes batch row tb==r),
      // teacher-force next dec_in
      float o[4];
#pragma unroll
      for(int i = 0; i < 4; ++i)
        o[i] = zbuf[th >> 2][tb][(th & 3)*4 + i] + ob[i];
      if(tb == r){
        float4 v; v.x = o[0]; v.y = o[1]; v.z = o[2]; v.w = o[3];
        *(float4*)(outD + ((size_t)(gb + tb)*1024 + d)*64 + th*4) = v;
      }
      if(tf[d] != 0){
        float4 xv = *(const float4*)(x + ((size_t)(gb + tb)*1024 + d)*64 + th*4);
        o[0] = xv.x; o[1] = xv.y; o[2] = xv.z; o[3] = xv.w;
      }
#pragma unroll
      for(int i = 0; i < 4; ++i) dinbuf[tb][th*4 + i] = (_Float16)o[i];
    }
    __syncthreads();
  }
}

// ---------------- main persistent kernel -----------------------------------
__global__ __launch_bounds__(256, 1)
void lstm_persist(const float* __restrict__ x, const int* __restrict__ lengths,
                  const int* __restrict__ tf,
                  const float* __restrict__ eb0, const float* __restrict__ eb1,
                  const float* __restrict__ db0, const float* __restrict__ db1,
                  const float* __restrict__ outb,
                  float* __restrict__ dout, char* __restrict__ ws)
{
  const int tid = threadIdx.x;
  __shared__ Shm sh;
  __shared__ int s_g, s_r, s_loc;

  // ---- XCD claim phase (dedicated immutable table) ----
  {
    int* tbl = (int*)(ws + OFF_TBL);
    int xcd;
    asm volatile("s_getreg_b32 %0, hwreg(HW_REG_XCC_ID)" : "=s"(xcd));
    if(tid == 0) stg_sys_i32(tbl + blockIdx.x, (xcd & 7) + 1);
    int* stbl = (int*)&sh.zbuf[0][0][0];
    if(tid < 128){
      int v = -1;
      for(int it = 0; it < 2000000; ++it){
        v = ldg_sys_i32(tbl + tid);
        if(v != -1) break;
      }
      stbl[tid] = v;
    }
    __syncthreads();
    if(tid == 0){
      int cnt[8] = {0,0,0,0,0,0,0,0};
      signed char gA[128], rA[128];
      for(int b = 0; b < 128; ++b){
        int xb = (stbl[b] - 1) & 7;
        if(cnt[xb] < 16){ gA[b] = (signed char)xb; rA[b] = (signed char)cnt[xb]++; }
        else gA[b] = -1;
      }
      int locmask = 0;
      for(int xx = 0; xx < 8; ++xx) if(cnt[xx] == 16) locmask |= (1 << xx);
      int dg = 0;
      for(int b = 0; b < 128; ++b) if(gA[b] < 0){
        while(cnt[dg] >= 16) ++dg;
        gA[b] = (signed char)dg; rA[b] = (signed char)cnt[dg]++;
      }
      int me = blockIdx.x;
      s_g = gA[me]; s_r = rA[me];
      s_loc = (locmask >> gA[me]) & 1;
    }
    __syncthreads();
  }
  const int g = s_g, r = s_r, loc = s_loc;
  __syncthreads();

  if(loc) core<true >(x, lengths, tf, eb0, eb1, db0, db1, outb, dout, ws, g, r, &sh);
  else    core<false>(x, lengths, tf, eb0, eb1, db0, db1, outb, dout, ws, g, r, &sh);
}

// ---------------------------------------------------------------------------
extern "C" void kernel_launch(void* const* d_in, const int* in_sizes, int n_in,
                              void* d_out, int out_size, void* d_ws, size_t ws_size,
                              hipStream_t stream){
  const float* x   = (const float*)d_in[0];
  const int* lens  = (const int*)d_in[1];
  const int* tfm   = (const int*)d_in[2];
  const float* eW0 = (const float*)d_in[3];
  const float* eU0 = (const float*)d_in[4];
  const float* eb0 = (const float*)d_in[5];
  const float* eW1 = (const float*)d_in[6];
  const float* eU1 = (const float*)d_in[7];
  const float* eb1 = (const float*)d_in[8];
  const float* dW0 = (const float*)d_in[9];
  const float* dU0 = (const float*)d_in[10];
  const float* db0 = (const float*)d_in[11];
  const float* dW1 = (const float*)d_in[12];
  const float* dU1 = (const float*)d_in[13];
  const float* db1 = (const float*)d_in[14];
  const float* oW  = (const float*)d_in[15];
  const float* ob  = (const float*)d_in[16];
  char* ws = (char*)d_ws;

  // ring init: slots 0..2 poison (0xFF), slot 3 zeros (h init state).
  // claim table (dedicated region): 0xFF == empty.
  hipMemsetAsync(ws + OFF_H0,            0xFF, 3*65536, stream);
  hipMemsetAsync(ws + OFF_H0 + 3*65536,  0x00, 65536,   stream);
  hipMemsetAsync(ws + OFF_H1,            0xFF, 3*65536, stream);
  hipMemsetAsync(ws + OFF_H1 + 3*65536,  0x00, 65536,   stream);
  hipMemsetAsync(ws + OFF_TBL,           0xFF, 512,     stream);
  lstm_xcvt <<<dim3(4096), dim3(256), 0, stream>>>(x, (_Float16*)(ws + OFF_XH));
  lstm_packw<<<dim3(840),  dim3(256), 0, stream>>>(eW0, eU0, eW1, eU1,
                                                   dW0, dU0, dW1, dU1, oW, ws);
  lstm_persist<<<dim3(128), dim3(256), 0, stream>>>(x, lens, tfm, eb0, eb1,
                                                    db0, db1, ob,
                                                    (float*)d_out, ws);
}

// Round 5
// 6531.270 us; speedup vs baseline: 1.8531x; 1.8531x over previous
//
#include <hip/hip_runtime.h>
#include <cstdint>
#include <cstddef>

// ---------------------------------------------------------------------------
// LSTM TF-autoencoder, persistent-kernel, poison-poll sync (no flags).
//  grid = 8 batch-groups (16 rows) x 16 gate-row slices = 128 blocks, 256 thr.
//
// THIS ROUND:
//  * FULL REVERT of coherence primitives to the R1 protocol (single
//    sc0 sc1 store, sc0 sc1 loads). The XCD-local L2 experiment is refuted
//    empirically: R3=10.8ms, R4=12.1ms vs R1=7.57ms even though FETCH
//    collapsed 6x -- mixed-scope stores + L2 poll contention cost more than
//    the LLC round-trip saves. Claim phase removed.
//  * DEFERRED h1 POLL / PROJECTION: when tf[d]==1, dec_in(d+1)=x (known), so
//    the h1(d) store->poll RT need not be paid inside step d. Step d+1
//    issues the h1(d) load at its top (no waitcnt), validates after GEMM0
//    (~0.8us of cover), then uses it BOTH as A1-right (cols [256,512)) and,
//    after the A1 sync, as the deferred projection's A operand in place
//    (gemm_tile<8> at Abuf+256 -- zero extra staging). outD(d) is written one
//    step late (not on the serial chain). The decoder-entry h1(enc,1023)
//    poll is deferred identically into step 0 (din(0)=x always).
//    Poison safety: my deferred validate precedes my h0(d) store; any other
//    block's poison of that h1 slot requires h0(d)-all incl. mine => ordered
//    after my validate. The stale h1-slot-2 poison moves to step 0
//    post-validate (same proof obligation as before).
//  * din staged from pre-converted Xh (f16 copy) instead of f32 x + cvt.
//
// Encoder is layer-skewed (iter t = layer0(t) + layer1(t-1)); decoder carries
// polled h0/h1 in VGPRs across steps.
// ---------------------------------------------------------------------------

typedef _Float16 f16x8 __attribute__((ext_vector_type(8)));
typedef float    f32x4 __attribute__((ext_vector_type(4)));
typedef unsigned int u32x4 __attribute__((ext_vector_type(4)));

#define AROWS 608  // LDS A-tile row stride in halfs

// workspace layout (bytes)
constexpr size_t OFF_E0  = 0;         // enc L0 packed [1024 x 320] f16
constexpr size_t OFF_E1  = 655360;    // enc L1 packed [1024 x 512] f16
constexpr size_t OFF_D0  = 1703936;   // dec L0 packed
constexpr size_t OFF_D1  = 2359296;   // dec L1 packed
constexpr size_t OFF_OW  = 3407872;   // out_W^T packed [256 x 64] f16
constexpr size_t OFF_H0  = 3440640;   // h0 ring: 4 slots x 65536 B
constexpr size_t OFF_H1  = 3702784;   // h1 ring: 4 slots x 65536 B
constexpr size_t OFF_XH  = 3964928;   // x in f16 [128][1024][64]
// slot layout (halfs): slot*32768 + g*4096 + r*256 + b*16 + th

// ---------------- coherent (LLC) access helpers ----------------------------
__device__ __forceinline__ void st_coh128(void* p, u32x4 v){
  asm volatile("global_store_dwordx4 %0, %1, off sc0 sc1"
               :: "v"((unsigned long long)(uintptr_t)p), "v"(v) : "memory");
}
__device__ __forceinline__ void ldg2_coh(const void* p0, const void* p1, u32x4& a, u32x4& b){
  asm volatile("global_load_dwordx4 %0, %2, off sc0 sc1\n\t"
               "global_load_dwordx4 %1, %3, off sc0 sc1\n\t"
               "s_waitcnt vmcnt(0)"
               : "=&v"(a), "=&v"(b)
               : "v"((unsigned long long)(uintptr_t)p0),
                 "v"((unsigned long long)(uintptr_t)p1) : "memory");
}
__device__ __forceinline__ void ldg4_coh(const void* p0, const void* p1, const void* p2, const void* p3,
                                         u32x4& a, u32x4& b, u32x4& c, u32x4& d){
  asm volatile("global_load_dwordx4 %0, %4, off sc0 sc1\n\t"
               "global_load_dwordx4 %1, %5, off sc0 sc1\n\t"
               "global_load_dwordx4 %2, %6, off sc0 sc1\n\t"
               "global_load_dwordx4 %3, %7, off sc0 sc1\n\t"
               "s_waitcnt vmcnt(0)"
               : "=&v"(a), "=&v"(b), "=&v"(c), "=&v"(d)
               : "v"((unsigned long long)(uintptr_t)p0),
                 "v"((unsigned long long)(uintptr_t)p1),
                 "v"((unsigned long long)(uintptr_t)p2),
                 "v"((unsigned long long)(uintptr_t)p3) : "memory");
}
// issue-only load pair (no waitcnt); pair with vm_wait0() before reading a/b.
__device__ __forceinline__ void ldg2_issue(const void* p0, const void* p1, u32x4& a, u32x4& b){
  asm volatile("global_load_dwordx4 %0, %2, off sc0 sc1\n\t"
               "global_load_dwordx4 %1, %3, off sc0 sc1"
               : "=&v"(a), "=&v"(b)
               : "v"((unsigned long long)(uintptr_t)p0),
                 "v"((unsigned long long)(uintptr_t)p1) : "memory");
}
__device__ __forceinline__ void vm_wait0(){
  asm volatile("s_waitcnt vmcnt(0)" ::: "memory");
  __builtin_amdgcn_sched_barrier(0);   // rule #18: block hoisting past the wait
}

// retry-poll two 16B chunks until no dword is poison (0xFFFFFFFF)
__device__ __forceinline__ void poll2(const void* p0, const void* p1,
                                      u32x4& a, u32x4& b, int& dead){
  if(dead) return;
  for(int gu = 0;; ++gu){
    ldg2_coh(p0, p1, a, b);
    unsigned bad = 0;
#pragma unroll
    for(int j = 0; j < 4; ++j) bad |= (a[j]==0xFFFFFFFFu) | (b[j]==0xFFFFFFFFu);
    if(!bad) return;
    if(gu > 60000){ dead = 1; return; }
  }
}

__device__ __forceinline__ float sigm(float z){ return 1.f/(1.f + __expf(-z)); }
__device__ __forceinline__ float tanh_(float z){ return 2.f/(1.f + __expf(-2.f*z)) - 1.f; }

template<int KS>
__device__ __forceinline__ f32x4 gemm_tile(const _Float16* A, int am, int q, const f16x8* wf){
  f32x4 a0 = {0.f,0.f,0.f,0.f}, a1 = {0.f,0.f,0.f,0.f};
#pragma unroll
  for(int ks = 0; ks < KS; ++ks){
    f16x8 av = *(const f16x8*)(A + am*AROWS + ks*32 + q*8);
    if(ks & 1) a1 = __builtin_amdgcn_mfma_f32_16x16x32_f16(av, wf[ks], a1, 0, 0, 0);
    else       a0 = __builtin_amdgcn_mfma_f32_16x16x32_f16(av, wf[ks], a0, 0, 0, 0);
  }
  return a0 + a1;
}

// ---------------- prep kernels ---------------------------------------------
__global__ void lstm_xcvt(const float* __restrict__ xin, _Float16* __restrict__ xh){
  size_t i = ((size_t)blockIdx.x * 256 + threadIdx.x) * 8;
  float4 a = *(const float4*)(xin + i);
  float4 b = *(const float4*)(xin + i + 4);
  union { _Float16 h[8]; u32x4 v; } o;
  o.h[0]=(_Float16)a.x; o.h[1]=(_Float16)a.y; o.h[2]=(_Float16)a.z; o.h[3]=(_Float16)a.w;
  o.h[4]=(_Float16)b.x; o.h[5]=(_Float16)b.y; o.h[6]=(_Float16)b.z; o.h[7]=(_Float16)b.w;
  *(u32x4*)(xh + i) = o.v;
}

__global__ void lstm_packw(const float* eW0, const float* eU0, const float* eW1, const float* eU1,
                           const float* dW0, const float* dU0, const float* dW1, const float* dU1,
                           const float* oW, char* ws){
  int c = blockIdx.x * 256 + threadIdx.x;
  const float *Wih, *Whh; _Float16* dst; int KS, Kin, cc;
  if(c < 40960)      { Wih=eW0; Whh=eU0; dst=(_Float16*)(ws+OFF_E0); KS=10; Kin=64;  cc=c; }
  else if(c < 106496){ Wih=eW1; Whh=eU1; dst=(_Float16*)(ws+OFF_E1); KS=16; Kin=256; cc=c-40960; }
  else if(c < 147456){ Wih=dW0; Whh=dU0; dst=(_Float16*)(ws+OFF_D0); KS=10; Kin=64;  cc=c-106496; }
  else if(c < 212992){ Wih=dW1; Whh=dU1; dst=(_Float16*)(ws+OFF_D1); KS=16; Kin=256; cc=c-147456; }
  else{
    cc = c - 212992;
    int l = cc & 63, t1 = cc >> 6, ks = t1 & 7, nt = t1 >> 3;
    int n = nt*16 + (l & 15), kb = ks*32 + ((l >> 4) << 3);
    union { _Float16 h[8]; u32x4 v; } o;
#pragma unroll
    for(int j = 0; j < 8; ++j) o.h[j] = (_Float16)oW[n*256 + kb + j];
    *(u32x4*)((_Float16*)(ws + OFF_OW) + (size_t)cc*8) = o.v;
    return;
  }
  int l = cc & 63, t1 = cc >> 6, ks, t2;
  if(KS == 10){ ks = t1 % 10; t2 = t1 / 10; } else { ks = t1 & 15; t2 = t1 >> 4; }
  int rr = t2 & 15, wg = t2 >> 4;
  int row = wg*256 + rr*16 + (l & 15);
  int kb  = ks*32 + ((l >> 4) << 3);
  union { _Float16 h[8]; u32x4 v; } o;
#pragma unroll
  for(int j = 0; j < 8; ++j){
    int k = kb + j;
    float s = (k < Kin) ? Wih[row*Kin + k] : Whh[row*256 + (k - Kin)];
    o.h[j] = (_Float16)s;
  }
  *(u32x4*)(dst + (size_t)cc*8) = o.v;
}

// ---------------- main persistent kernel -----------------------------------
__global__ __launch_bounds__(256, 1)
void lstm_persist(const float* __restrict__ x, const int* __restrict__ lengths,
                  const int* __restrict__ tf,
                  const float* __restrict__ eb0, const float* __restrict__ eb1,
                  const float* __restrict__ db0, const float* __restrict__ db1,
                  const float* __restrict__ outb,
                  float* __restrict__ dout, char* __restrict__ ws)
{
  const int tid = threadIdx.x;
  const int lane = tid & 63, w = tid >> 6;
  const int g = blockIdx.x >> 4, r = blockIdx.x & 15;
  const int gb = g * 16;
  const int tb = tid >> 4, th = tid & 15;
  const int am = lane & 15, q = lane >> 4;
  const int m0 = tid >> 5, kc = tid & 31;
  const int hco = (kc >> 1)*256 + (kc & 1)*8 + m0*16 + g*4096; // + slot*32768
  const int slice = g*4096 + r*256;                            // writer slice base

  _Float16* Xh    = (_Float16*)(ws + OFF_XH);
  _Float16* h0buf = (_Float16*)(ws + OFF_H0);
  _Float16* h1buf = (_Float16*)(ws + OFF_H1);
  float* outD = dout;
  float* outE = dout + (size_t)128*1024*64;

  __shared__ alignas(16) _Float16 Abuf[16*AROWS];
  __shared__ float zbuf[4][16][17];
  __shared__ float zbuf2[4][16][17];   // deferred-projection output
  __shared__ alignas(16) _Float16 dinbuf[16][80];
  __shared__ alignas(16) _Float16 hsh[256];

  float c0 = 0.f, c1 = 0.f, h0p = 0.f, h1p = 0.f;
  const int len_b = lengths[gb + tb];
  int dead = 0;
  const u32x4 PZ = {0xFFFFFFFFu,0xFFFFFFFFu,0xFFFFFFFFu,0xFFFFFFFFu};

  u32x4 H0ra, H0rb;  // carried full-h0 chunks
  u32x4 H1ca, H1cb;  // carried full-h1 chunks

  float be0[4], be1[4];
#pragma unroll
  for(int j = 0; j < 4; ++j){
    be0[j] = eb0[j*256 + r*16 + th];
    be1[j] = eb1[j*256 + r*16 + th];
  }

  f16x8 wf0[10], wf1[16], wfo[8];
  {
    const f16x8* p0 = (const f16x8*)(ws + OFF_E0);
    const f16x8* p1 = (const f16x8*)(ws + OFF_E1);
#pragma unroll
    for(int ks = 0; ks < 10; ++ks) wf0[ks] = p0[((w*16 + r)*10 + ks)*64 + lane];
#pragma unroll
    for(int ks = 0; ks < 16; ++ks) wf1[ks] = p1[((w*16 + r)*16 + ks)*64 + lane];
  }

  // ===================== ENCODER (layer-skewed, R1 protocol) ================
  for(int t = 0; t <= 1024; ++t){
    const int sh0 = (t+3)&3;   // h0(t-1) read slot
    const int sh1 = (t+2)&3;   // h1(t-2) read slot
    u32x4 a, b, H1a, H1b;
    const _Float16 *h1q0, *h1q1;

    // ---- stage: x_t + h0(t-1); issue h1(t-2) (validated after cell0) ----
    if(t < 1024 && tid < 128){
      int mm = tid >> 3, k0 = (tid & 7) * 8;
      *(f16x8*)(Abuf + mm*AROWS + k0) =
          *(const f16x8*)(Xh + ((size_t)(gb + mm)*1024 + t)*64 + k0);
    }
    {
      const _Float16* b0 = h0buf + sh0*32768 + hco;
      const _Float16* b1 = b0 + 128;
      h1q0 = h1buf + sh1*32768 + hco;
      h1q1 = h1q0 + 128;
      ldg4_coh(b0, b1, h1q0, h1q1, a, b, H1a, H1b);
      unsigned bad = 0;
#pragma unroll
      for(int j = 0; j < 4; ++j) bad |= (a[j]==0xFFFFFFFFu) | (b[j]==0xFFFFFFFFu);
      if(bad) poll2(b0, b1, a, b, dead);
      *(f16x8*)(Abuf + m0*AROWS + 64 + kc*8)     = __builtin_bit_cast(f16x8, a);
      *(f16x8*)(Abuf + (m0+8)*AROWS + 64 + kc*8) = __builtin_bit_cast(f16x8, b);
      H0ra = a; H0rb = b;   // live-out at t==1024: h0(enc,1023) for decoder A0
    }
    __syncthreads();

    if(t < 1024){
      { // layer0 GEMM
        f32x4 z = gemm_tile<10>(Abuf, am, q, wf0);
#pragma unroll
        for(int i = 0; i < 4; ++i) zbuf[w][q*4 + i][am] = z[i];
      }
      __syncthreads();
      { // layer0 cell (freeze past length)
        float zi = zbuf[0][tb][th] + be0[0];
        float zf = zbuf[1][tb][th] + be0[1];
        float zg = zbuf[2][tb][th] + be0[2];
        float zo = zbuf[3][tb][th] + be0[3];
        float cn = sigm(zf)*c0 + sigm(zi)*tanh_(zg);
        float hn = sigm(zo)*tanh_(cn);
        bool valid = t < len_b;
        c0  = valid ? cn : c0;
        h0p = valid ? hn : h0p;
        hsh[tb*16 + th] = (_Float16)h0p;
      }
      __syncthreads();
      if(tid < 32)
        st_coh128(h0buf + (t&3)*32768 + slice + tid*8, *(const u32x4*)&hsh[tid*8]);
    }

    if(t >= 1){
      // ---- validate h1(t-2), stage A[320,576), poison ----
      unsigned bad = 0;
#pragma unroll
      for(int j = 0; j < 4; ++j) bad |= (H1a[j]==0xFFFFFFFFu) | (H1b[j]==0xFFFFFFFFu);
      if(bad) poll2(h1q0, h1q1, H1a, H1b, dead);
      *(f16x8*)(Abuf + m0*AROWS + 320 + kc*8)     = __builtin_bit_cast(f16x8, H1a);
      *(f16x8*)(Abuf + (m0+8)*AROWS + 320 + kc*8) = __builtin_bit_cast(f16x8, H1b);
      if(tid < 64){
        _Float16* basep = (tid < 32) ? (h0buf + ((t+2)&3)*32768)
                                     : (h1buf + ((t+1)&3)*32768);
        st_coh128(basep + slice + (tid&31)*8, PZ);
      }
      __syncthreads();

      { // layer1 GEMM (step t-1)
        f32x4 z = gemm_tile<16>(Abuf + 64, am, q, wf1);
#pragma unroll
        for(int i = 0; i < 4; ++i) zbuf[w][q*4 + i][am] = z[i];
      }
      __syncthreads();
      { // layer1 cell for step u = t-1 (+ encoder output)
        const int u = t - 1;
        float zi = zbuf[0][tb][th] + be1[0];
        float zf = zbuf[1][tb][th] + be1[1];
        float zg = zbuf[2][tb][th] + be1[2];
        float zo = zbuf[3][tb][th] + be1[3];
        float cn = sigm(zf)*c1 + sigm(zi)*tanh_(zg);
        float hn = sigm(zo)*tanh_(cn);
        bool valid = u < len_b;
        c1  = valid ? cn : c1;
        h1p = valid ? hn : h1p;
        outE[((size_t)(gb + tb)*1024 + u)*256 + r*16 + th] = valid ? h1p : 0.f;
        hsh[tb*16 + th] = (_Float16)h1p;
      }
      __syncthreads();
      if(tid < 32)
        st_coh128(h1buf + ((t+3)&3)*32768 + slice + tid*8, *(const u32x4*)&hsh[tid*8]);
    }
  }

  // ===================== phase switch =====================
  {
    const f16x8* p0 = (const f16x8*)(ws + OFF_D0);
    const f16x8* p1 = (const f16x8*)(ws + OFF_D1);
    const f16x8* po = (const f16x8*)(ws + OFF_OW);
#pragma unroll
    for(int ks = 0; ks < 10; ++ks) wf0[ks] = p0[((w*16 + r)*10 + ks)*64 + lane];
#pragma unroll
    for(int ks = 0; ks < 16; ++ks) wf1[ks] = p1[((w*16 + r)*16 + ks)*64 + lane];
#pragma unroll
    for(int ks = 0; ks < 8;  ++ks) wfo[ks] = po[(w*8 + ks)*64 + lane];
  }
  float bd0[4], bd1[4], ob[4];
#pragma unroll
  for(int j = 0; j < 4; ++j){
    bd0[j] = db0[j*256 + r*16 + th];
    bd1[j] = db1[j*256 + r*16 + th];
    ob[j]  = outb[th*4 + j];
  }
  // dec_in init = x[:, T-1, :] (f16 copy from Xh)
  if(tid < 128){
    int mm = tid >> 3, k0 = (tid & 7) * 8;
    *(f16x8*)(&dinbuf[mm][k0]) =
        *(const f16x8*)(Xh + ((size_t)(gb + mm)*1024 + 1023)*64 + k0);
  }
  __syncthreads();
  // NOTE: h1(enc,1023) poll (slot 3) is DEFERRED into decoder step 0.

  // ===================== DECODER (deferred h1 poll/projection) ==============
  int tfprev = 0;
  for(int d = 0; d < 1024; ++d){
    const int s4 = d & 3;
    const int Pdef = (d == 0) | tfprev;   // h1(d-1) ring poll deferred to now
    const int Pout = (d > 0) & tfprev;    // outD(d-1) pending
    u32x4 Pa, Pb;
    const _Float16* pq0 = h1buf + ((d+3)&3)*32768 + hco;  // h1(d-1) slot
    const _Float16* pq1 = pq0 + 128;

    // ---- phase 1: A0 stage + deferred h1 issue ----
    if(Pdef) ldg2_issue(pq0, pq1, Pa, Pb);
    if(tid < 128){
      int mm = tid >> 3, k0 = (tid & 7) * 8;
      *(f16x8*)(Abuf + mm*AROWS + k0) = *(const f16x8*)(&dinbuf[mm][k0]);
    }
    *(f16x8*)(Abuf + m0*AROWS + 64 + kc*8)     = __builtin_bit_cast(f16x8, H0ra);
    *(f16x8*)(Abuf + (m0+8)*AROWS + 64 + kc*8) = __builtin_bit_cast(f16x8, H0rb);
    __syncthreads();

    // ---- phase 2: GEMM0 ----
    {
      f32x4 z = gemm_tile<10>(Abuf, am, q, wf0);
#pragma unroll
      for(int i = 0; i < 4; ++i) zbuf[w][q*4 + i][am] = z[i];
    }
    __syncthreads();

    // ---- phase 3: deferred h1(d-1) validate; cell0 ----
    if(Pdef){
      vm_wait0();
      unsigned bad = 0;
#pragma unroll
      for(int j = 0; j < 4; ++j) bad |= (Pa[j]==0xFFFFFFFFu) | (Pb[j]==0xFFFFFFFFu);
      if(bad) poll2(pq0, pq1, Pa, Pb, dead);
      H1ca = Pa; H1cb = Pb;
      // d==0: h1(enc,1023)-all valid => all blocks finished the encoder
      // drain => stale h1 slot 2 (h1(enc,1022)) is dead; poison it.
      if(d == 0 && tid < 32)
        st_coh128(h1buf + 2*32768 + slice + tid*8, PZ);
    }
    { // layer0 cell
      float zi = zbuf[0][tb][th] + bd0[0];
      float zf = zbuf[1][tb][th] + bd0[1];
      float zg = zbuf[2][tb][th] + bd0[2];
      float zo = zbuf[3][tb][th] + bd0[3];
      float cn = sigm(zf)*c0 + sigm(zi)*tanh_(zg);
      float hn = sigm(zo)*tanh_(cn);
      c0 = cn;
      hsh[tb*16 + th] = (_Float16)hn;
    }
    __syncthreads();

    // ---- phase 4: store h0(d); stage A1; poll h0(d); poison ----
    if(tid < 32)
      st_coh128(h0buf + s4*32768 + slice + tid*8, *(const u32x4*)&hsh[tid*8]);
    *(f16x8*)(Abuf + m0*AROWS + 256 + kc*8)     = __builtin_bit_cast(f16x8, H1ca);
    *(f16x8*)(Abuf + (m0+8)*AROWS + 256 + kc*8) = __builtin_bit_cast(f16x8, H1cb);
    {
      const _Float16* b0 = h0buf + s4*32768 + hco;
      const _Float16* b1 = b0 + 128;
      u32x4 a, b;
      ldg2_coh(b0, b1, a, b);
      unsigned bad = 0;
#pragma unroll
      for(int j = 0; j < 4; ++j) bad |= (a[j]==0xFFFFFFFFu) | (b[j]==0xFFFFFFFFu);
      if(bad) poll2(b0, b1, a, b, dead);
      *(f16x8*)(Abuf + m0*AROWS + kc*8)       = __builtin_bit_cast(f16x8, a);
      *(f16x8*)(Abuf + (m0+8)*AROWS + kc*8)   = __builtin_bit_cast(f16x8, b);
      H0ra = a; H0rb = b;
    }
    // h0(d)-all valid => every block finished step d-1 (incl. its deferred
    // h1(d-1) validate, which precedes its h0(d) store) => poison is safe.
    if(tid < 64){
      _Float16* basep = ((tid < 32) ? h0buf : h1buf) + ((d+3)&3)*32768;
      st_coh128(basep + slice + (tid&31)*8, PZ);
    }
    __syncthreads();

    // ---- phase 5: deferred projection (A = h1(d-1) resident at +256) + GEMM1
    if(Pout){
      f32x4 z = gemm_tile<8>(Abuf + 256, am, q, wfo);
#pragma unroll
      for(int i = 0; i < 4; ++i) zbuf2[w][q*4 + i][am] = z[i];
    }
    {
      f32x4 z = gemm_tile<16>(Abuf, am, q, wf1);
#pragma unroll
      for(int i = 0; i < 4; ++i) zbuf[w][q*4 + i][am] = z[i];
    }
    __syncthreads();

    // ---- phase 6: deferred outD(d-1) write; cell1 ----
    if(Pout && tb == r){
      float4 v;
      v.x = zbuf2[th >> 2][tb][(th & 3)*4 + 0] + ob[0];
      v.y = zbuf2[th >> 2][tb][(th & 3)*4 + 1] + ob[1];
      v.z = zbuf2[th >> 2][tb][(th & 3)*4 + 2] + ob[2];
      v.w = zbuf2[th >> 2][tb][(th & 3)*4 + 3] + ob[3];
      *(float4*)(outD + ((size_t)(gb + tb)*1024 + (d-1))*64 + th*4) = v;
    }
    { // layer1 cell
      float zi = zbuf[0][tb][th] + bd1[0];
      float zf = zbuf[1][tb][th] + bd1[1];
      float zg = zbuf[2][tb][th] + bd1[2];
      float zo = zbuf[3][tb][th] + bd1[3];
      float cn = sigm(zf)*c1 + sigm(zi)*tanh_(zg);
      float hn = sigm(zo)*tanh_(cn);
      c1 = cn;
      hsh[tb*16 + th] = (_Float16)hn;
    }
    __syncthreads();

    // ---- phase 7: store h1(d); din(d+1) ----
    if(tid < 32)
      st_coh128(h1buf + s4*32768 + slice + tid*8, *(const u32x4*)&hsh[tid*8]);
    const int tfcur = tf[d];
    if(tfcur != 0){
      // teacher forcing: din(d+1) = x[:,d,:] -- defer h1(d) poll + proj(d).
      if(tid < 128){
        int mm = tid >> 3, k0 = (tid & 7) * 8;
        *(f16x8*)(&dinbuf[mm][k0]) =
            *(const f16x8*)(Xh + ((size_t)(gb + mm)*1024 + d)*64 + k0);
      }
    } else {
      // poll h1(d) now; proj; din(d+1) = out(d)
      const _Float16* b0 = h1buf + s4*32768 + hco;
      const _Float16* b1 = b0 + 128;
      ldg2_coh(b0, b1, H1ca, H1cb);
      unsigned bad = 0;
#pragma unroll
      for(int j = 0; j < 4; ++j) bad |= (H1ca[j]==0xFFFFFFFFu) | (H1cb[j]==0xFFFFFFFFu);
      if(bad) poll2(b0, b1, H1ca, H1cb, dead);
      *(f16x8*)(Abuf + m0*AROWS + kc*8)     = __builtin_bit_cast(f16x8, H1ca);
      *(f16x8*)(Abuf + (m0+8)*AROWS + kc*8) = __builtin_bit_cast(f16x8, H1cb);
      __syncthreads();
      {
        f32x4 z = gemm_tile<8>(Abuf, am, q, wfo);
#pragma unroll
        for(int i = 0; i < 4; ++i) zbuf[w][q*4 + i][am] = z[i];
      }
      __syncthreads();
      {
        float o[4];
#pragma unroll
        for(int i = 0; i < 4; ++i)
          o[i] = zbuf[th >> 2][tb][(th & 3)*4 + i] + ob[i];
        if(tb == r){
          float4 v; v.x = o[0]; v.y = o[1]; v.z = o[2]; v.w = o[3];
          *(float4*)(outD + ((size_t)(gb + tb)*1024 + d)*64 + th*4) = v;
        }
#pragma unroll
        for(int i = 0; i < 4; ++i) dinbuf[tb][th*4 + i] = (_Float16)o[i];
      }
    }
    __syncthreads();
    tfprev = tfcur;
  }

  // ---- drain: pending projection for d=1023 if it was a tf step ----
  if(tfprev != 0){
    const _Float16* b0 = h1buf + 3*32768 + hco;   // 1023 & 3 == 3
    const _Float16* b1 = b0 + 128;
    u32x4 a, b;
    ldg2_coh(b0, b1, a, b);
    unsigned bad = 0;
#pragma unroll
    for(int j = 0; j < 4; ++j) bad |= (a[j]==0xFFFFFFFFu) | (b[j]==0xFFFFFFFFu);
    if(bad) poll2(b0, b1, a, b, dead);
    *(f16x8*)(Abuf + m0*AROWS + kc*8)     = __builtin_bit_cast(f16x8, a);
    *(f16x8*)(Abuf + (m0+8)*AROWS + kc*8) = __builtin_bit_cast(f16x8, b);
    __syncthreads();
    {
      f32x4 z = gemm_tile<8>(Abuf, am, q, wfo);
#pragma unroll
      for(int i = 0; i < 4; ++i) zbuf[w][q*4 + i][am] = z[i];
    }
    __syncthreads();
    if(tb == r){
      float4 v;
      v.x = zbuf[th >> 2][tb][(th & 3)*4 + 0] + ob[0];
      v.y = zbuf[th >> 2][tb][(th & 3)*4 + 1] + ob[1];
      v.z = zbuf[th >> 2][tb][(th & 3)*4 + 2] + ob[2];
      v.w = zbuf[th >> 2][tb][(th & 3)*4 + 3] + ob[3];
      *(float4*)(outD + ((size_t)(gb + tb)*1024 + 1023)*64 + th*4) = v;
    }
  }
}

// ---------------------------------------------------------------------------
extern "C" void kernel_launch(void* const* d_in, const int* in_sizes, int n_in,
                              void* d_out, int out_size, void* d_ws, size_t ws_size,
                              hipStream_t stream){
  const float* x   = (const float*)d_in[0];
  const int* lens  = (const int*)d_in[1];
  const int* tfm   = (const int*)d_in[2];
  const float* eW0 = (const float*)d_in[3];
  const float* eU0 = (const float*)d_in[4];
  const float* eb0 = (const float*)d_in[5];
  const float* eW1 = (const float*)d_in[6];
  const float* eU1 = (const float*)d_in[7];
  const float* eb1 = (const float*)d_in[8];
  const float* dW0 = (const float*)d_in[9];
  const float* dU0 = (const float*)d_in[10];
  const float* db0 = (const float*)d_in[11];
  const float* dW1 = (const float*)d_in[12];
  const float* dU1 = (const float*)d_in[13];
  const float* db1 = (const float*)d_in[14];
  const float* oW  = (const float*)d_in[15];
  const float* ob  = (const float*)d_in[16];
  char* ws = (char*)d_ws;

  // ring init: slots 0..2 poison (0xFF), slot 3 zeros (h init state)
  hipMemsetAsync(ws + OFF_H0,            0xFF, 3*65536, stream);
  hipMemsetAsync(ws + OFF_H0 + 3*65536,  0x00, 65536,   stream);
  hipMemsetAsync(ws + OFF_H1,            0xFF, 3*65536, stream);
  hipMemsetAsync(ws + OFF_H1 + 3*65536,  0x00, 65536,   stream);
  lstm_xcvt <<<dim3(4096), dim3(256), 0, stream>>>(x, (_Float16*)(ws + OFF_XH));
  lstm_packw<<<dim3(840),  dim3(256), 0, stream>>>(eW0, eU0, eW1, eU1,
                                                   dW0, dU0, dW1, dU1, oW, ws);
  lstm_persist<<<dim3(128), dim3(256), 0, stream>>>(x, lens, tfm, eb0, eb1,
                                                    db0, db1, ob,
                                                    (float*)d_out, ws);
}